// Round 7
// baseline (181.390 us; speedup 1.0000x reference)
//
#include <hip/hip_runtime.h>

// Problem constants (match reference)
#define K_     1056
#define N_     2112
#define M_     1056   // N - K
#define E_     6336   // M * 6
#define NIE_   5280   // M * 5 info-side edges (the only BP state)
#define CAP_   6336   // padded c2v extent upper bound (stride = d|1 adds <=1/VN)
#define ALL_   7392   // CAP_ + K_ : c2v + marg unified array (float2 units)
#define DV_    5
#define ROW_   6      // edge 6m+5 is the parity VN K+m
#define NSYM_  528
#define NITER_ 20
#define BATCH_ 1024
#define BS_    1024   // 16 waves/block, 2 blocks/CU = 32 waves
#define NCW_   2      // codewords per block (float2-packed payload)
#define TAIL_  32     // K_ - BS_ : items handled by the LDS-state tail path

#define LOG2E_ 1.4426950408889634f
#define AVLO_  (1e-6f * LOG2E_)          // |v2c| floor, bits units
#define AVHI_  (20.0f * LOG2E_)          // |v2c| cap,  bits units
#define QC_    0.99999988f               // tanh-domain cap (unchanged)

// stride(d) = d | 1 : always ODD -> coprime with the 16 bank-pairs of a
// b64 access -> Phase A's wave-uniform-stride segment reads stay
// conflict-free in the float2 layout.
__device__ __forceinline__ int seg_stride(int d) { return d | 1; }

// Bare-instruction transcendentals (R17 win: OCML wrappers inflated the
// hot loop ~2x; inputs always normal-range, <=1 ULP deviation validated
// absmax-0 since R1).
__device__ __forceinline__ float fexp2(float x) { return __builtin_amdgcn_exp2f(x); }
__device__ __forceinline__ float flog2(float x) { return __builtin_amdgcn_logf(x); }
__device__ __forceinline__ float frcp(float x)  { return __builtin_amdgcn_rcpf(x); }

// -------------------------------------------------------------------------
// Single kernel, TWO codewords per block, 1024 threads / 16 waves.
// == R26: R25 dual-codeword float2 BP + spill-free register budget ==
//
// R25 won (112.5us, conflicts 1.94e7->1.34e7) but spilled ~53MB scratch:
// its trip-1 (kk=1) register file exists for only 32/1024 threads yet is
// allocated wave-uniformly (vnp[1]+c2v[1]+t5/od/lr ~ 22 dwords), blowing
// the (1024,8) cap of 64 unified regs (32 arch + 32 AGPR).
// R26: trip-0 state ONLY in registers (20 dwords persistent, peak live
// ~45 <= 64 -> AGPR-absorbed, zero scratch; same live/cap regime as
// R21's clean point). Trip-1 state (32 threads) lives in ~1.3KB of LDS
// side arrays; trip-1's old c2v is RE-READ from the edge slot (R19
// identity: at Phase-B time the slot holds last iter's r; single writer
// per edge -> no hazard). Extra cost ~10 LDS ops x 32 threads/iter.
// Per-codeword fp sequences verbatim -> absmax 0 by construction
// (storage location change only; mgv - slot == mgv - c2v_reg exactly).
// Spill check: WRITE_SIZE == ~8450 KB.
//
// LDS map (float2 units, s_all2[7392] = 59136 B):
//   [0..CAP)   build: [0..N) staging (VN i -> {llr_cw0, llr_cw1}),
//              [N..N+2112) = 4224 ints of build scratch;
//              BP: c2v odd-stride VN-major segments (r-values)
//   [CAP..ALL) slot-indexed marginals (float2)
// + side arrays: s_vnp2[160], s_od2[32], s_lr2/s_t52[32] f2 (~1.3 KB)
//
// Structure: H = [A | I]; parity VN deg-1 -> per-check constant t5;
// degree-sorted slots (wave-uniform Phase A trips); scan-free bases from
// 32-bin histogram; od packs base|deg<<13|pv<<18; atomic build order
// only permutes accumulation order (validated order-independent R4-R25).
//
// CN math per component (prefix/suffix partial products, bits domain):
//   t = copysign((1-2^-av)/(1+2^-av), v2c);  q_j = t5 * prod_{i!=j} t_i
//   q = med3(q, -QC, QC);  r = log2((1+q)/(1-q))
// -------------------------------------------------------------------------
__global__ __launch_bounds__(BS_, 8) void link_kernel(
    const int*   __restrict__ bits,      // [B,K]
    const int*   __restrict__ a_idx,     // [M,DV]
    const float* __restrict__ points_re, // [16]
    const float* __restrict__ points_im, // [16]
    const float* __restrict__ noise_re,  // [B,NSYM]
    const float* __restrict__ noise_im,  // [B,NSYM]
    const float* __restrict__ ebno_db,   // [1]
    const int*   __restrict__ edge_vn,   // [E]
    float*       __restrict__ out)       // [2,B,K]
{
#pragma clang fp contract(off)
    const int blk = blockIdx.x;
    const int b0  = blk * NCW_;          // codeword 0 (component .x)
    const int b1  = b0 + 1;              // codeword 1 (component .y)
    const int tid = threadIdx.x;

    __shared__ float2 s_all2[ALL_];
    __shared__ float  s_pre[16];
    __shared__ float  s_pim[16];
    __shared__ int    s_hist[32];
    __shared__ int    s_binStart[32];
    __shared__ int    s_binBase[32];
    // R26 tail-state side arrays (trip-1 items, 32 threads)
    __shared__ unsigned s_vnp2[TAIL_ * 5];
    __shared__ unsigned s_od2[TAIL_];
    __shared__ float2   s_lr2[TAIL_];
    __shared__ float2   s_t52[TAIL_];

    float* s_f = (float*)s_all2;         // scalar view (component access)
    char*  sb  = (char*)s_all2;          // byte view (Phase B addressing)

    // build scratch aliases: float2 [N..N+2112) = 4224 ints (demap uses [0..N))
    int* sc        = (int*)(s_all2 + N_);
    int* s_deg     = sc;                 // [K] degree
    int* s_perm    = sc + K_;            // [K] slot -> v | deg<<16
    int* s_offslot = sc + 2 * K_;        // [K] v -> base | slot<<16
    int* s_cnt     = sc + 3 * K_;        // [K] edge-fill cursors

    if (tid < 16) {
        s_pre[tid] = points_re[tid];
        s_pim[tid] = points_im[tid];
    }
    if (tid < 32) s_hist[tid] = 0;

    const float eb    = ebno_db[0];
    const float no    = 1.0f / ((powf(10.0f, eb / 10.0f) * 0.5f) * 4.0f);
    const float sigma = sqrtf(no / 2.0f);

    // ---- stage info bits (0/1 floats, both codewords); out0 = bits ----
    for (int i = tid; i < K_; i += BS_) {
        int v0 = bits[b0 * K_ + i];
        int v1 = bits[b1 * K_ + i];
        s_f[2 * i + 0] = (float)v0;
        s_f[2 * i + 1] = (float)v1;
        out[b0 * K_ + i] = (float)v0;
        out[b1 * K_ + i] = (float)v1;
    }
    __syncthreads();

    // ---- parity: XOR of DV gathered info bits (both cw, b64 gathers) ----
    for (int m = tid; m < M_; m += BS_) {
        float ax = 0.0f, ay = 0.0f;
        #pragma unroll
        for (int d = 0; d < DV_; ++d) {
            float2 f = s_all2[a_idx[m * DV_ + d]];
            ax += f.x; ay += f.y;
        }
        float2 p;
        p.x = (float)(((int)ax) & 1);
        p.y = (float)(((int)ay) & 1);
        s_all2[K_ + m] = p;
    }
    for (int v = tid; v < K_; v += BS_) { s_deg[v] = 0; s_cnt[v] = 0; }
    __syncthreads();

    // ---- QAM + AWGN + exact APP demap, per-(symbol,codeword) tasks ----
    // ---- overlapped: VN degree count (disjoint LDS region)         ----
    for (int tsk = tid; tsk < NCW_ * NSYM_; tsk += BS_) {
        int cw = (tsk >= NSYM_) ? 1 : 0;
        int s  = tsk - cw * NSYM_;
        int bcw = b0 + cw;
        int c0 = (int)s_f[2 * (4 * s + 0) + cw];
        int c1 = (int)s_f[2 * (4 * s + 1) + cw];
        int c2 = (int)s_f[2 * (4 * s + 2) + cw];
        int c3 = (int)s_f[2 * (4 * s + 3) + cw];
        int sym = c0 * 8 + c1 * 4 + c2 * 2 + c3;
        float yre = s_pre[sym] + sigma * noise_re[bcw * NSYM_ + s];
        float yim = s_pim[sym] + sigma * noise_im[bcw * NSYM_ + s];
        #pragma unroll
        for (int j = 0; j < 4; ++j) {
            // pass 1: maxes for bit j (ascending p, same comparisons)
            float m0 = -1e30f, m1 = -1e30f;
            #pragma unroll
            for (int p = 0; p < 16; ++p) {
                float dre  = yre - s_pre[p];
                float dim_ = yim - s_pim[p];
                float lg   = -(dre * dre + dim_ * dim_) / no;
                if (((p >> (3 - j)) & 1) == 0) m0 = fmaxf(m0, lg);
                else                           m1 = fmaxf(m1, lg);
            }
            // pass 2: sums for bit j (identical fp sequence, ascending p)
            float sum0 = 0.0f, sum1 = 0.0f;
            #pragma unroll
            for (int p = 0; p < 16; ++p) {
                float dre  = yre - s_pre[p];
                float dim_ = yim - s_pim[p];
                float lg   = -(dre * dre + dim_ * dim_) / no;
                if (((p >> (3 - j)) & 1) == 0) sum0 += __expf(lg - m0);
                else                           sum1 += __expf(lg - m1);
            }
            float llr = (m0 + __logf(sum0)) - (m1 + __logf(sum1));
            s_f[2 * (4 * s + j) + cw] = llr * LOG2E_;
        }
    }
    for (int idx = tid; idx < NIE_; idx += BS_) {
        int m = idx / 5, j = idx - m * 5;
        atomicAdd(&s_deg[edge_vn[m * ROW_ + j]], 1);
    }
    __syncthreads();

    // ---- degree histogram -> arithmetic segment bases (scan-free) ----
    for (int v = tid; v < K_; v += BS_) atomicAdd(&s_hist[s_deg[v] & 31], 1);
    __syncthreads();
    if (tid == 0) {
        int accS = 0, accB = 0;
        for (int d = 0; d < 32; ++d) {
            int c = s_hist[d];
            s_binStart[d] = accS;
            s_binBase[d]  = accB;
            s_hist[d]     = accS;        // reuse as sort cursor
            accS += c;
            accB += c * seg_stride(d);   // odd stride -> conflict-free
        }
    }
    __syncthreads();
    for (int v = tid; v < K_; v += BS_) {   // counting sort by degree
        int d    = s_deg[v];
        int slot = atomicAdd(&s_hist[d & 31], 1);
        int base = s_binBase[d] + (slot - s_binStart[d]) * seg_stride(d);
        s_perm[slot]  = v | (d << 16);
        s_offslot[v]  = base | (slot << 16);
    }
    __syncthreads();

    // ---- capture iteration-invariant state ----
    // trip 0 (all threads): REGISTERS.  od0 = base | deg<<13 | pv<<18
    unsigned od0;
    float2   lr0;
    {
        int w = s_perm[tid];
        int v = w & 0xFFFF;
        int d = w >> 16;
        int base = s_binBase[d] + (tid - s_binStart[d]) * seg_stride(d);
        od0 = (unsigned)base | ((unsigned)d << 13) | ((unsigned)v << 18);
        lr0 = s_all2[v];
        s_all2[CAP_ + tid] = lr0;        // iter-0 marginal == channel LLR
    }
    // trip 1 (tid<32): LDS side arrays (VN side)
    if (tid < TAIL_) {
        int s = tid + BS_;
        int w = s_perm[s];
        int v = w & 0xFFFF;
        int d = w >> 16;
        int base = s_binBase[d] + (s - s_binStart[d]) * seg_stride(d);
        s_od2[tid] = (unsigned)base | ((unsigned)d << 13) | ((unsigned)v << 18);
        float2 l = s_all2[v];
        s_lr2[tid] = l;
        s_all2[CAP_ + s] = l;
    }
    // trip 0 CN state: REGISTERS
    float2   t50;
    unsigned vnp0[5];                    // slotByte | eposByte<<16 (x8 units)
    float2   c2v0[5];                    // c2v register file (both cw)
    {
        int m = tid;
        #pragma unroll
        for (int j = 0; j < 5; ++j) {
            int v = edge_vn[m * ROW_ + j];
            int r = atomicAdd(&s_cnt[v], 1);
            int w = s_offslot[v];
            int slot = w >> 16;
            int epos = (w & 0xFFFF) + r;
            vnp0[j] = (unsigned)(slot << 3) | ((unsigned)(epos << 3) << 16);
            c2v0[j] = make_float2(0.0f, 0.0f);
        }
        float2 lrP = s_all2[K_ + m];
        float avx = __builtin_amdgcn_fmed3f(fabsf(lrP.x), AVLO_, AVHI_);
        float avy = __builtin_amdgcn_fmed3f(fabsf(lrP.y), AVLO_, AVHI_);
        float ex  = fexp2(-avx), ey = fexp2(-avy);
        float tmx = (1.0f - ex) * frcp(1.0f + ex);
        float tmy = (1.0f - ey) * frcp(1.0f + ey);
        t50 = make_float2(copysignf(tmx, lrP.x), copysignf(tmy, lrP.y));
    }
    // trip 1 CN state (tid<32): LDS side arrays; c2v re-read from edge
    // slots during B (slot holds last iter's r — R19 identity).
    if (tid < TAIL_) {
        int m = tid + BS_;
        #pragma unroll
        for (int j = 0; j < 5; ++j) {
            int v = edge_vn[m * ROW_ + j];
            int r = atomicAdd(&s_cnt[v], 1);
            int w = s_offslot[v];
            int slot = w >> 16;
            int epos = (w & 0xFFFF) + r;
            s_vnp2[tid * 5 + j] = (unsigned)(slot << 3) |
                                  ((unsigned)(epos << 3) << 16);
        }
        float2 lrP = s_all2[K_ + m];
        float avx = __builtin_amdgcn_fmed3f(fabsf(lrP.x), AVLO_, AVHI_);
        float avy = __builtin_amdgcn_fmed3f(fabsf(lrP.y), AVLO_, AVHI_);
        float ex  = fexp2(-avx), ey = fexp2(-avy);
        float tmx = (1.0f - ex) * frcp(1.0f + ex);
        float tmy = (1.0f - ey) * frcp(1.0f + ey);
        s_t52[tid] = make_float2(copysignf(tmx, lrP.x), copysignf(tmy, lrP.y));
    }
    __syncthreads();
    // staging + build scratch fully consumed -> zero edge-slot array
    for (int i = tid; i < CAP_; i += BS_) s_all2[i] = make_float2(0.0f, 0.0f);
    __syncthreads();

    // ---- sum-product BP, flooding (bits domain), {B; A} x NITER ----
    for (int it = 0; it < NITER_; ++it) {
        // Phase B trip 0: CN update, both codewords per b64 LDS op; old
        // c2v from registers; bare v_exp/v_log/v_rcp.
        {
            float tjx[5], tjy[5];
            #pragma unroll
            for (int j = 0; j < 5; ++j) {
                unsigned w = vnp0[j];
                float2 mgv = *(const float2*)(sb +
                             ((w & 0xFFFFu) + (unsigned)(CAP_ * 8)));
                float vx = mgv.x - c2v0[j].x;
                float vy = mgv.y - c2v0[j].y;
                float avx = __builtin_amdgcn_fmed3f(fabsf(vx), AVLO_, AVHI_);
                float avy = __builtin_amdgcn_fmed3f(fabsf(vy), AVLO_, AVHI_);
                float ex = fexp2(-avx), ey = fexp2(-avy);
                float tmx = (1.0f - ex) * frcp(1.0f + ex);
                float tmy = (1.0f - ey) * frcp(1.0f + ey);
                tjx[j] = copysignf(tmx, vx);
                tjy[j] = copysignf(tmy, vy);
            }
            float qx[5], qy[5];
            float prx = t50.x, pry = t50.y;
            #pragma unroll
            for (int j = 0; j < 5; ++j) {
                qx[j] = prx; qy[j] = pry;
                prx *= tjx[j]; pry *= tjy[j];
            }
            float sfx = 1.0f, sfy = 1.0f;
            #pragma unroll
            for (int j = 4; j >= 0; --j) {
                qx[j] *= sfx; qy[j] *= sfy;
                sfx *= tjx[j]; sfy *= tjy[j];
            }
            #pragma unroll
            for (int j = 0; j < 5; ++j) {
                float qcx = __builtin_amdgcn_fmed3f(qx[j], -QC_, QC_);
                float qcy = __builtin_amdgcn_fmed3f(qy[j], -QC_, QC_);
                float rx = flog2((1.0f + qcx) * frcp(1.0f - qcx));
                float ry = flog2((1.0f + qcy) * frcp(1.0f - qcy));
                c2v0[j] = make_float2(rx, ry);
                *(float2*)(sb + (vnp0[j] >> 16)) = c2v0[j];
            }
        }
        // Phase B trip 1 (tid<32): vnp from LDS; old c2v re-read from the
        // edge slot (identical value: slot holds last iter's r).
        if (tid < TAIL_) {
            unsigned ww[5];
            float tjx[5], tjy[5];
            #pragma unroll
            for (int j = 0; j < 5; ++j) {
                unsigned w = s_vnp2[tid * 5 + j];
                ww[j] = w;
                float2 mgv = *(const float2*)(sb +
                             ((w & 0xFFFFu) + (unsigned)(CAP_ * 8)));
                float2 oldc = *(const float2*)(sb + (w >> 16));
                float vx = mgv.x - oldc.x;
                float vy = mgv.y - oldc.y;
                float avx = __builtin_amdgcn_fmed3f(fabsf(vx), AVLO_, AVHI_);
                float avy = __builtin_amdgcn_fmed3f(fabsf(vy), AVLO_, AVHI_);
                float ex = fexp2(-avx), ey = fexp2(-avy);
                float tmx = (1.0f - ex) * frcp(1.0f + ex);
                float tmy = (1.0f - ey) * frcp(1.0f + ey);
                tjx[j] = copysignf(tmx, vx);
                tjy[j] = copysignf(tmy, vy);
            }
            float2 t5v = s_t52[tid];
            float qx[5], qy[5];
            float prx = t5v.x, pry = t5v.y;
            #pragma unroll
            for (int j = 0; j < 5; ++j) {
                qx[j] = prx; qy[j] = pry;
                prx *= tjx[j]; pry *= tjy[j];
            }
            float sfx = 1.0f, sfy = 1.0f;
            #pragma unroll
            for (int j = 4; j >= 0; --j) {
                qx[j] *= sfx; qy[j] *= sfy;
                sfx *= tjx[j]; sfy *= tjy[j];
            }
            #pragma unroll
            for (int j = 0; j < 5; ++j) {
                float qcx = __builtin_amdgcn_fmed3f(qx[j], -QC_, QC_);
                float qcy = __builtin_amdgcn_fmed3f(qy[j], -QC_, QC_);
                float rx = flog2((1.0f + qcx) * frcp(1.0f - qcx));
                float ry = flog2((1.0f + qcy) * frcp(1.0f - qcy));
                *(float2*)(sb + (ww[j] >> 16)) = make_float2(rx, ry);
            }
        }
        __syncthreads();
        // Phase A trip 0: slot-indexed marginals; odd-stride sequential
        // b64 segment reads. Last iteration doubles as final decision.
        {
            int base = (int)(od0 & 0x1FFFu);
            int dg   = (int)((od0 >> 13) & 31u);
            float mgx = lr0.x, mgy = lr0.y;
            int d = 0;
            for (; d + 1 < dg; d += 2) {
                float2 f0 = s_all2[base + d];
                float2 f1 = s_all2[base + d + 1];
                mgx += f0.x; mgy += f0.y;
                mgx += f1.x; mgy += f1.y;
            }
            if (d < dg) {
                float2 f0 = s_all2[base + d];
                mgx += f0.x; mgy += f0.y;
            }
            s_all2[CAP_ + tid] = make_float2(mgx, mgy);
            if (it == NITER_ - 1) {
                int pv = (int)(od0 >> 18);
                out[(size_t)BATCH_ * K_ + b0 * K_ + pv] = (mgx < 0.0f) ? 1.0f : 0.0f;
                out[(size_t)BATCH_ * K_ + b1 * K_ + pv] = (mgy < 0.0f) ? 1.0f : 0.0f;
            }
        }
        // Phase A trip 1 (tid<32): state from LDS side arrays.
        if (tid < TAIL_) {
            unsigned odv = s_od2[tid];
            float2   lrv = s_lr2[tid];
            int s    = tid + BS_;
            int base = (int)(odv & 0x1FFFu);
            int dg   = (int)((odv >> 13) & 31u);
            float mgx = lrv.x, mgy = lrv.y;
            int d = 0;
            for (; d + 1 < dg; d += 2) {
                float2 f0 = s_all2[base + d];
                float2 f1 = s_all2[base + d + 1];
                mgx += f0.x; mgy += f0.y;
                mgx += f1.x; mgy += f1.y;
            }
            if (d < dg) {
                float2 f0 = s_all2[base + d];
                mgx += f0.x; mgy += f0.y;
            }
            s_all2[CAP_ + s] = make_float2(mgx, mgy);
            if (it == NITER_ - 1) {
                int pv = (int)(odv >> 18);
                out[(size_t)BATCH_ * K_ + b0 * K_ + pv] = (mgx < 0.0f) ? 1.0f : 0.0f;
                out[(size_t)BATCH_ * K_ + b1 * K_ + pv] = (mgy < 0.0f) ? 1.0f : 0.0f;
            }
        }
        __syncthreads();
    }
}

extern "C" void kernel_launch(void* const* d_in, const int* in_sizes, int n_in,
                              void* d_out, int out_size, void* d_ws, size_t ws_size,
                              hipStream_t stream) {
    const int*   bits    = (const int*)  d_in[0];
    const int*   a_idx   = (const int*)  d_in[1];
    // d_in[2] = edge_cn (implicit: contiguous groups of 6) — unused
    const int*   edge_vn = (const int*)  d_in[3];
    const float* pre     = (const float*)d_in[4];
    const float* pim     = (const float*)d_in[5];
    const float* nre     = (const float*)d_in[6];
    const float* nim     = (const float*)d_in[7];
    const float* ebno    = (const float*)d_in[8];

    link_kernel<<<BATCH_ / NCW_, BS_, 0, stream>>>(bits, a_idx, pre, pim, nre, nim,
                                                   ebno, edge_vn, (float*)d_out);
}

// Round 8
// 172.661 us; speedup vs baseline: 1.0506x; 1.0506x over previous
//
#include <hip/hip_runtime.h>

// Problem constants (match reference)
#define K_     1056
#define N_     2112
#define M_     1056   // N - K
#define E_     6336   // M * 6
#define NIE_   5280   // M * 5 info-side edges (the only BP state)
#define CAP_   6336   // padded c2v extent upper bound (stride = d|1 adds <=1/VN)
#define ALL_   7392   // CAP_ + K_ : c2v + marg unified array (float2 units)
#define DV_    5
#define ROW_   6      // edge 6m+5 is the parity VN K+m
#define NSYM_  528
#define NITER_ 20
#define BATCH_ 1024
#define BS_    1024   // 16 waves/block, 2 blocks/CU = 32 waves
#define KMAX_  2      // ceil(K_/BS_) work trips per thread
#define NCW_   2      // codewords per block (float2-packed payload)

#define LOG2E_ 1.4426950408889634f
#define AVLO_  (1e-6f * LOG2E_)          // |v2c| floor, bits units
#define AVHI_  (20.0f * LOG2E_)          // |v2c| cap,  bits units
#define QC_    0.99999988f               // tanh-domain cap (unchanged)

// R27: ext_vector pair type -> backend emits v_pk_add_f32/v_pk_mul_f32
// (two independent IEEE fp32 lanes per instruction; per-component
// rounding identical to scalar -> bit-exact vs R25).
typedef float f2 __attribute__((ext_vector_type(2)));

// stride(d) = d | 1 : always ODD -> coprime with the 16 bank-pairs of a
// b64 access -> Phase A's wave-uniform-stride segment reads stay
// conflict-free in the float2 layout.
__device__ __forceinline__ int seg_stride(int d) { return d | 1; }

// Bare-instruction transcendentals (R17 win: OCML wrappers inflated the
// hot loop ~2x; inputs always normal-range, <=1 ULP deviation validated
// absmax-0 since R1).
__device__ __forceinline__ float fexp2(float x) { return __builtin_amdgcn_exp2f(x); }
__device__ __forceinline__ float flog2(float x) { return __builtin_amdgcn_logf(x); }
__device__ __forceinline__ float frcp(float x)  { return __builtin_amdgcn_rcpf(x); }

// -------------------------------------------------------------------------
// Single kernel, TWO codewords per block, 1024 threads / 16 waves.
// == R27: R25 dual-codeword BP + packed-fp32 (v_pk) component math ==
//
// R25 (112.5us, best) counter budget: conflicts 19%, LDS issue ~22%,
// VALU/trans issue ~71% -> VALU pipe is the floor. R26's tail-to-LDS
// de-spill attempt regressed (120.5us) -> reverted; R25's ~53MB scratch
// spill is mostly latency-hidden and cheaper than every alternative
// tried (R21/R22/R24/R26).
// R27: all pairwise mul/add/sub on the {cw0,cw1} payload is written as
// ext_vector_type(2) arithmetic -> v_pk_*_f32 (one instruction, two
// fp32 lanes, per-lane IEEE identical). Halves the packable ~70% of
// VALU issue. Transcendentals (exp2/log2/rcp), med3, copysign stay
// scalar per component (no pk forms). fp contract(off) -> no fma
// fusion -> per-component op sequence unchanged -> absmax 0.
//
// LDS map (f2 units, s_all2[7392] = 59136 B):
//   [0..CAP)   build: [0..N) staging (VN i -> {llr_cw0, llr_cw1}),
//              [N..N+2112) = 4224 ints of build scratch;
//              BP: c2v odd-stride VN-major segments (r-values)
//   [CAP..ALL) slot-indexed marginals (f2)
//
// Structure: H = [A | I]; parity VN deg-1 -> per-check constant t5;
// degree-sorted slots (wave-uniform Phase A trips); scan-free bases from
// 32-bin histogram; od packs base|deg<<13|pv<<18; atomic build order
// only permutes accumulation order (validated order-independent R4-R26).
//
// CN math per component (prefix/suffix partial products, bits domain):
//   t = copysign((1-2^-av)/(1+2^-av), v2c);  q_j = t5 * prod_{i!=j} t_i
//   q = med3(q, -QC, QC);  r = log2((1+q)/(1-q))
// -------------------------------------------------------------------------
__global__ __launch_bounds__(BS_, 8) void link_kernel(
    const int*   __restrict__ bits,      // [B,K]
    const int*   __restrict__ a_idx,     // [M,DV]
    const float* __restrict__ points_re, // [16]
    const float* __restrict__ points_im, // [16]
    const float* __restrict__ noise_re,  // [B,NSYM]
    const float* __restrict__ noise_im,  // [B,NSYM]
    const float* __restrict__ ebno_db,   // [1]
    const int*   __restrict__ edge_vn,   // [E]
    float*       __restrict__ out)       // [2,B,K]
{
#pragma clang fp contract(off)
    const int blk = blockIdx.x;
    const int b0  = blk * NCW_;          // codeword 0 (component .x)
    const int b1  = b0 + 1;              // codeword 1 (component .y)
    const int tid = threadIdx.x;

    __shared__ f2   s_all2[ALL_];
    __shared__ float s_pre[16];
    __shared__ float s_pim[16];
    __shared__ int   s_hist[32];
    __shared__ int   s_binStart[32];
    __shared__ int   s_binBase[32];

    float* s_f = (float*)s_all2;         // scalar view (component access)
    char*  sb  = (char*)s_all2;          // byte view (Phase B addressing)

    // build scratch aliases: f2 [N..N+2112) = 4224 ints (demap uses [0..N))
    int* sc        = (int*)(s_all2 + N_);
    int* s_deg     = sc;                 // [K] degree
    int* s_perm    = sc + K_;            // [K] slot -> v | deg<<16
    int* s_offslot = sc + 2 * K_;        // [K] v -> base | slot<<16
    int* s_cnt     = sc + 3 * K_;        // [K] edge-fill cursors

    if (tid < 16) {
        s_pre[tid] = points_re[tid];
        s_pim[tid] = points_im[tid];
    }
    if (tid < 32) s_hist[tid] = 0;

    const float eb    = ebno_db[0];
    const float no    = 1.0f / ((powf(10.0f, eb / 10.0f) * 0.5f) * 4.0f);
    const float sigma = sqrtf(no / 2.0f);

    // ---- stage info bits (0/1 floats, both codewords); out0 = bits ----
    for (int i = tid; i < K_; i += BS_) {
        int v0 = bits[b0 * K_ + i];
        int v1 = bits[b1 * K_ + i];
        s_f[2 * i + 0] = (float)v0;
        s_f[2 * i + 1] = (float)v1;
        out[b0 * K_ + i] = (float)v0;
        out[b1 * K_ + i] = (float)v1;
    }
    __syncthreads();

    // ---- parity: XOR of DV gathered info bits (both cw, pk adds) ----
    for (int m = tid; m < M_; m += BS_) {
        f2 acc = (f2)0.0f;
        #pragma unroll
        for (int d = 0; d < DV_; ++d) acc = acc + s_all2[a_idx[m * DV_ + d]];
        f2 p;
        p.x = (float)(((int)acc.x) & 1);
        p.y = (float)(((int)acc.y) & 1);
        s_all2[K_ + m] = p;
    }
    for (int v = tid; v < K_; v += BS_) { s_deg[v] = 0; s_cnt[v] = 0; }
    __syncthreads();

    // ---- QAM + AWGN + exact APP demap, per-(symbol,codeword) tasks ----
    // ---- overlapped: VN degree count (disjoint LDS region)         ----
    for (int tsk = tid; tsk < NCW_ * NSYM_; tsk += BS_) {
        int cw = (tsk >= NSYM_) ? 1 : 0;
        int s  = tsk - cw * NSYM_;
        int bcw = b0 + cw;
        int c0 = (int)s_f[2 * (4 * s + 0) + cw];
        int c1 = (int)s_f[2 * (4 * s + 1) + cw];
        int c2 = (int)s_f[2 * (4 * s + 2) + cw];
        int c3 = (int)s_f[2 * (4 * s + 3) + cw];
        int sym = c0 * 8 + c1 * 4 + c2 * 2 + c3;
        float yre = s_pre[sym] + sigma * noise_re[bcw * NSYM_ + s];
        float yim = s_pim[sym] + sigma * noise_im[bcw * NSYM_ + s];
        #pragma unroll
        for (int j = 0; j < 4; ++j) {
            // pass 1: maxes for bit j (ascending p, same comparisons)
            float m0 = -1e30f, m1 = -1e30f;
            #pragma unroll
            for (int p = 0; p < 16; ++p) {
                float dre  = yre - s_pre[p];
                float dim_ = yim - s_pim[p];
                float lg   = -(dre * dre + dim_ * dim_) / no;
                if (((p >> (3 - j)) & 1) == 0) m0 = fmaxf(m0, lg);
                else                           m1 = fmaxf(m1, lg);
            }
            // pass 2: sums for bit j (identical fp sequence, ascending p)
            float sum0 = 0.0f, sum1 = 0.0f;
            #pragma unroll
            for (int p = 0; p < 16; ++p) {
                float dre  = yre - s_pre[p];
                float dim_ = yim - s_pim[p];
                float lg   = -(dre * dre + dim_ * dim_) / no;
                if (((p >> (3 - j)) & 1) == 0) sum0 += __expf(lg - m0);
                else                           sum1 += __expf(lg - m1);
            }
            float llr = (m0 + __logf(sum0)) - (m1 + __logf(sum1));
            s_f[2 * (4 * s + j) + cw] = llr * LOG2E_;
        }
    }
    for (int idx = tid; idx < NIE_; idx += BS_) {
        int m = idx / 5, j = idx - m * 5;
        atomicAdd(&s_deg[edge_vn[m * ROW_ + j]], 1);
    }
    __syncthreads();

    // ---- degree histogram -> arithmetic segment bases (scan-free) ----
    for (int v = tid; v < K_; v += BS_) atomicAdd(&s_hist[s_deg[v] & 31], 1);
    __syncthreads();
    if (tid == 0) {
        int accS = 0, accB = 0;
        for (int d = 0; d < 32; ++d) {
            int c = s_hist[d];
            s_binStart[d] = accS;
            s_binBase[d]  = accB;
            s_hist[d]     = accS;        // reuse as sort cursor
            accS += c;
            accB += c * seg_stride(d);   // odd stride -> conflict-free
        }
    }
    __syncthreads();
    for (int v = tid; v < K_; v += BS_) {   // counting sort by degree
        int d    = s_deg[v];
        int slot = atomicAdd(&s_hist[d & 31], 1);
        int base = s_binBase[d] + (slot - s_binStart[d]) * seg_stride(d);
        s_perm[slot]  = v | (d << 16);
        s_offslot[v]  = base | (slot << 16);
    }
    __syncthreads();

    // ---- capture iteration-invariant state in registers ----
    unsigned od[KMAX_];                  // base | deg<<13 | pv<<18
    f2       lr[KMAX_];                  // channel LLR_hat (both cw)
    #pragma unroll
    for (int k = 0; k < KMAX_; ++k) {
        int s = tid + BS_ * k;
        if (s < K_) {
            int w = s_perm[s];
            int v = w & 0xFFFF;
            int d = w >> 16;
            int base = s_binBase[d] + (s - s_binStart[d]) * seg_stride(d);
            od[k] = (unsigned)base | ((unsigned)d << 13) | ((unsigned)v << 18);
            lr[k] = s_all2[v];
            s_all2[CAP_ + s] = lr[k];    // iter-0 marginal == channel LLR
        } else { od[k] = 0; lr[k] = (f2)0.0f; }
    }
    f2       t5[KMAX_];
    unsigned vnp[KMAX_][5];              // slotByte | eposByte<<16 (x8 units)
    f2       c2v[KMAX_][5];              // c2v register file (both cw)
    #pragma unroll
    for (int kk = 0; kk < KMAX_; ++kk) {
        int m = tid + BS_ * kk;
        if (m < M_) {
            #pragma unroll
            for (int j = 0; j < 5; ++j) {
                int v = edge_vn[m * ROW_ + j];
                int r = atomicAdd(&s_cnt[v], 1);
                int w = s_offslot[v];
                int slot = w >> 16;
                int epos = (w & 0xFFFF) + r;
                vnp[kk][j] = (unsigned)(slot << 3) | ((unsigned)(epos << 3) << 16);
                c2v[kk][j] = (f2)0.0f;
            }
            f2 lrP = s_all2[K_ + m];
            float avx = __builtin_amdgcn_fmed3f(fabsf(lrP.x), AVLO_, AVHI_);
            float avy = __builtin_amdgcn_fmed3f(fabsf(lrP.y), AVLO_, AVHI_);
            f2 e2; e2.x = fexp2(-avx); e2.y = fexp2(-avy);
            f2 om = 1.0f - e2;           // pk
            f2 op = 1.0f + e2;           // pk
            f2 u2; u2.x = frcp(op.x); u2.y = frcp(op.y);
            f2 tm2 = om * u2;            // pk
            f2 t;
            t.x = copysignf(tm2.x, lrP.x);
            t.y = copysignf(tm2.y, lrP.y);
            t5[kk] = t;
        } else {
            t5[kk] = (f2)0.0f;
            #pragma unroll
            for (int j = 0; j < 5; ++j) {
                vnp[kk][j] = 0; c2v[kk][j] = (f2)0.0f;
            }
        }
    }
    __syncthreads();
    // staging + build scratch fully consumed -> zero edge-slot array
    for (int i = tid; i < CAP_; i += BS_) s_all2[i] = (f2)0.0f;
    __syncthreads();

    // ---- sum-product BP, flooding (bits domain), {B; A} x NITER ----
    for (int it = 0; it < NITER_; ++it) {
        // Phase B: CN update, both codewords per b64 LDS op; old c2v from
        // registers; pk mul/add pairs + scalar trans per component.
        #pragma unroll
        for (int kk = 0; kk < KMAX_; ++kk) {
            int m = tid + BS_ * kk;
            if (m < M_) {
                f2 tj[5];
                #pragma unroll
                for (int j = 0; j < 5; ++j) {
                    unsigned w = vnp[kk][j];
                    f2 mgv = *(const f2*)(sb +
                             ((w & 0xFFFFu) + (unsigned)(CAP_ * 8)));
                    f2 v2 = mgv - c2v[kk][j];          // pk sub
                    float avx = __builtin_amdgcn_fmed3f(fabsf(v2.x), AVLO_, AVHI_);
                    float avy = __builtin_amdgcn_fmed3f(fabsf(v2.y), AVLO_, AVHI_);
                    f2 e2; e2.x = fexp2(-avx); e2.y = fexp2(-avy);
                    f2 om = 1.0f - e2;                 // pk
                    f2 op = 1.0f + e2;                 // pk
                    f2 u2; u2.x = frcp(op.x); u2.y = frcp(op.y);
                    f2 tm2 = om * u2;                  // pk
                    f2 t;
                    t.x = copysignf(tm2.x, v2.x);
                    t.y = copysignf(tm2.y, v2.y);
                    tj[j] = t;
                }
                f2 q[5];
                f2 pr = t5[kk];
                #pragma unroll
                for (int j = 0; j < 5; ++j) {
                    q[j] = pr;
                    pr = pr * tj[j];                   // pk
                }
                f2 sf = (f2)1.0f;
                #pragma unroll
                for (int j = 4; j >= 0; --j) {
                    q[j] = q[j] * sf;                  // pk
                    sf = sf * tj[j];                   // pk
                }
                #pragma unroll
                for (int j = 0; j < 5; ++j) {
                    f2 qc;
                    qc.x = __builtin_amdgcn_fmed3f(q[j].x, -QC_, QC_);
                    qc.y = __builtin_amdgcn_fmed3f(q[j].y, -QC_, QC_);
                    f2 opq = 1.0f + qc;                // pk
                    f2 omq = 1.0f - qc;                // pk
                    f2 w2; w2.x = frcp(omq.x); w2.y = frcp(omq.y);
                    f2 ar = opq * w2;                  // pk
                    f2 r; r.x = flog2(ar.x); r.y = flog2(ar.y);
                    c2v[kk][j] = r;
                    *(f2*)(sb + (vnp[kk][j] >> 16)) = r;
                }
            }
        }
        __syncthreads();
        // Phase A: slot-indexed marginals; odd-stride sequential b64
        // segment reads, pk adds. Last iteration doubles as the final
        // marginal + hard decision.
        #pragma unroll
        for (int k = 0; k < KMAX_; ++k) {
            int s = tid + BS_ * k;
            if (s < K_) {
                int base = (int)(od[k] & 0x1FFFu);
                int dg   = (int)((od[k] >> 13) & 31u);
                f2 mg = lr[k];
                int d = 0;
                for (; d + 1 < dg; d += 2) {
                    mg = mg + s_all2[base + d];        // pk
                    mg = mg + s_all2[base + d + 1];    // pk
                }
                if (d < dg) mg = mg + s_all2[base + d];// pk
                s_all2[CAP_ + s] = mg;
                if (it == NITER_ - 1) {
                    int pv = (int)(od[k] >> 18);
                    out[(size_t)BATCH_ * K_ + b0 * K_ + pv] = (mg.x < 0.0f) ? 1.0f : 0.0f;
                    out[(size_t)BATCH_ * K_ + b1 * K_ + pv] = (mg.y < 0.0f) ? 1.0f : 0.0f;
                }
            }
        }
        __syncthreads();
    }
}

extern "C" void kernel_launch(void* const* d_in, const int* in_sizes, int n_in,
                              void* d_out, int out_size, void* d_ws, size_t ws_size,
                              hipStream_t stream) {
    const int*   bits    = (const int*)  d_in[0];
    const int*   a_idx   = (const int*)  d_in[1];
    // d_in[2] = edge_cn (implicit: contiguous groups of 6) — unused
    const int*   edge_vn = (const int*)  d_in[3];
    const float* pre     = (const float*)d_in[4];
    const float* pim     = (const float*)d_in[5];
    const float* nre     = (const float*)d_in[6];
    const float* nim     = (const float*)d_in[7];
    const float* ebno    = (const float*)d_in[8];

    link_kernel<<<BATCH_ / NCW_, BS_, 0, stream>>>(bits, a_idx, pre, pim, nre, nim,
                                                   ebno, edge_vn, (float*)d_out);
}